// Round 6
// baseline (654.546 us; speedup 1.0000x reference)
//
#include <hip/hip_runtime.h>

#define NN 20000
#define NE 640000
#define Cc 128
#define C2 256
#define BN_EPS 1e-5f

// ---- workspace layout (float offsets) ----
#define WS_P     0                      // [NN*Cc]
#define WS_Q     (NN*Cc)                // [NN*Cc]
#define WS_CNTT  (2*NN*Cc)              // [NN] float
#define WS_CNTS  (2*NN*Cc + NN)         // [NN] int
#define WS_STATS (2*NN*Cc + 2*NN)       // [768]: sum1[256], sq1[256], sum2[128], sq2[128]
#define WS_W1PT  (WS_STATS + 768)       // [256*128] transposed folded W1: [c][o]
#define WS_B1P   (WS_W1PT + C2*Cc)      // [128]
#define WS_W2T   (WS_B1P + Cc)          // [128*128] transposed folded W2: [c][o]
#define WS_B2P   (WS_W2T + Cc*Cc)       // [128]

// nbr_sum [NN*Cc] lives in the first 10.24MB of d_out (scratch until k_pq, then
// fully overwritten by k_out).

__global__ void k_zero(float* __restrict__ stats, int* __restrict__ cntS) {
  int i = blockIdx.x * blockDim.x + threadIdx.x;
  if (i < 768) stats[i] = 0.0f;
  if (i < NN) cntS[i] = 0;
}

__global__ void k_cnt(const int* __restrict__ src, int* __restrict__ cntS) {
  int e = blockIdx.x * blockDim.x + threadIdx.x;
  if (e < NE) atomicAdd(&cntS[src[e]], 1);
}

// one block (128 threads) per node: segment sum of x[src] over the node's
// contiguous (tgt sorted) edge range, found by binary search.
__global__ void k_nbr(const float* __restrict__ x, const int* __restrict__ tgt,
                      const int* __restrict__ src, float* __restrict__ nbr,
                      float* __restrict__ cntT) {
  int node = blockIdx.x;
  int a = 0, b = NE;
  while (a < b) { int m = (a + b) >> 1; if (tgt[m] < node) a = m + 1; else b = m; }
  int lo = a;
  b = NE;
  while (a < b) { int m = (a + b) >> 1; if (tgt[m] <= node) a = m + 1; else b = m; }
  int hi = a;
  int c = threadIdx.x;
  float acc = 0.0f;
  for (int e = lo; e < hi; ++e) acc += x[src[e] * Cc + c];
  nbr[node * Cc + c] = acc;
  if (c == 0) cntT[node] = (float)(hi - lo);
}

// BN1 stats: count-weighted sums over nodes. thread = channel (0..127 handles
// both halves: c from nbr part, 128+c from x part).
__global__ void k_stats1(const float* __restrict__ nbr, const float* __restrict__ x,
                         const float* __restrict__ cntT, const int* __restrict__ cntS,
                         float* __restrict__ stats) {
  int c = threadIdx.x;
  float sa = 0.f, qa = 0.f, sb = 0.f, qb = 0.f;
  for (int t = blockIdx.x; t < NN; t += gridDim.x) {
    float ct = cntT[t];
    float cs = (float)cntS[t];
    float v1 = nbr[t * Cc + c];
    float v2 = x[t * Cc + c];
    sa += ct * v1; qa += ct * v1 * v1;
    sb += cs * v2; qb += cs * v2 * v2;
  }
  atomicAdd(&stats[c], sa);
  atomicAdd(&stats[256 + c], qa);
  atomicAdd(&stats[128 + c], sb);
  atomicAdd(&stats[256 + 128 + c], qb);
}

// fold BN1 into W1: W1pT[c][o] = W1[o][c]*a1[c];  b1p[o] = b1[o] + sum_c W1[o][c]*c1[c]
__global__ void k_fold1(const float* __restrict__ W1, const float* __restrict__ b1,
                        const float* __restrict__ g1, const float* __restrict__ be1,
                        const float* __restrict__ stats,
                        float* __restrict__ W1pT, float* __restrict__ b1p) {
  __shared__ float red[C2];
  int o = blockIdx.x, c = threadIdx.x;
  const float inv = 1.0f / (float)NE;
  float mu = stats[c] * inv;
  float var = stats[256 + c] * inv - mu * mu;
  float a = g1[c] * rsqrtf(var + BN_EPS);
  float cc = be1[c] - mu * a;
  float w = W1[o * C2 + c];
  W1pT[c * Cc + o] = w * a;
  red[c] = w * cc;
  __syncthreads();
  for (int s = 128; s > 0; s >>= 1) { if (c < s) red[c] += red[c + s]; __syncthreads(); }
  if (c == 0) b1p[o] = b1[o] + red[0];
}

// P = nbr_sum @ W1a'.T ; Q = x @ W1b'.T   (blockIdx.y selects half)
// 32 rows per block, 256 threads, 4x4 register tile, W read from global (L1/L2 hot).
__global__ __launch_bounds__(256) void k_pq(const float* __restrict__ nbr,
                                            const float* __restrict__ x,
                                            const float* __restrict__ W1pT,
                                            float* __restrict__ P,
                                            float* __restrict__ Q) {
  __shared__ float Ar[32][128];
  const int half = blockIdx.y;
  const float* __restrict__ A = half ? x : nbr;
  float* __restrict__ Out = half ? Q : P;
  const float* __restrict__ Wt = W1pT + (half ? Cc * Cc : 0);  // [128 c][128 o]
  int tid = threadIdx.x;
  int r0 = blockIdx.x * 32;
  for (int i = tid; i < 32 * 128; i += 256) {
    int r = i >> 7, c = i & 127;
    Ar[r][c] = A[(r0 + r) * Cc + c];
  }
  __syncthreads();
  int tx = tid & 31, ty = tid >> 5;
  float acc[4][4] = {};
  #pragma unroll 4
  for (int c = 0; c < 128; ++c) {
    float4 w = *(const float4*)&Wt[c * Cc + tx * 4];
    float a0 = Ar[ty * 4 + 0][c], a1 = Ar[ty * 4 + 1][c];
    float a2 = Ar[ty * 4 + 2][c], a3 = Ar[ty * 4 + 3][c];
    acc[0][0] += a0 * w.x; acc[0][1] += a0 * w.y; acc[0][2] += a0 * w.z; acc[0][3] += a0 * w.w;
    acc[1][0] += a1 * w.x; acc[1][1] += a1 * w.y; acc[1][2] += a1 * w.z; acc[1][3] += a1 * w.w;
    acc[2][0] += a2 * w.x; acc[2][1] += a2 * w.y; acc[2][2] += a2 * w.z; acc[2][3] += a2 * w.w;
    acc[3][0] += a3 * w.x; acc[3][1] += a3 * w.y; acc[3][2] += a3 * w.z; acc[3][3] += a3 * w.w;
  }
  #pragma unroll
  for (int i = 0; i < 4; ++i) {
    int node = r0 + ty * 4 + i;
    float4 v = make_float4(acc[i][0], acc[i][1], acc[i][2], acc[i][3]);
    *(float4*)&Out[node * Cc + tx * 4] = v;
  }
}

// BN2 stats: one pass over edges, z recomputed from P,Q (L2-resident).
__global__ void k_stats2(const float* __restrict__ P, const float* __restrict__ Q,
                         const float* __restrict__ b1p,
                         const int* __restrict__ tgt, const int* __restrict__ src,
                         float* __restrict__ stats) {
  int c = threadIdx.x;
  int e0 = blockIdx.x * 512;
  float b = b1p[c];
  float s = 0.f, q = 0.f;
  for (int e = e0; e < e0 + 512; ++e) {
    int t = tgt[e], sc = src[e];
    float z = P[t * Cc + c] + Q[sc * Cc + c] + b;
    z = fmaxf(z, 0.f);
    s += z; q += z * z;
  }
  atomicAdd(&stats[512 + c], s);
  atomicAdd(&stats[640 + c], q);
}

__global__ void k_fold2(const float* __restrict__ W2, const float* __restrict__ b2,
                        const float* __restrict__ g2, const float* __restrict__ be2,
                        const float* __restrict__ stats,
                        float* __restrict__ W2t, float* __restrict__ b2p) {
  __shared__ float red[Cc];
  int o = blockIdx.x, c = threadIdx.x;
  const float inv = 1.0f / (float)NE;
  float mu = stats[512 + c] * inv;
  float var = stats[640 + c] * inv - mu * mu;
  float a = g2[c] * rsqrtf(var + BN_EPS);
  float cc = be2[c] - mu * a;
  float w = W2[o * Cc + c];
  W2t[c * Cc + o] = w * a;
  red[c] = w * cc;
  __syncthreads();
  for (int s = 64; s > 0; s >>= 1) { if (c < s) red[c] += red[c + s]; __syncthreads(); }
  if (c == 0) b2p[o] = b2[o] + red[0];
}

// out[e][o] = relu( sum_c z[e][c]*W2'[o][c] + b2'[o] ), z recomputed on the fly.
// 32 edges/block, 256 threads, 4x4 register tile, W2t from global (hot in cache).
__global__ __launch_bounds__(256) void k_out(const float* __restrict__ P,
                                             const float* __restrict__ Q,
                                             const float* __restrict__ b1p,
                                             const float* __restrict__ W2t,
                                             const float* __restrict__ b2p,
                                             const int* __restrict__ tgt,
                                             const int* __restrict__ src,
                                             float* __restrict__ out) {
  __shared__ float Z[32][128];
  int tid = threadIdx.x;
  int e0 = blockIdx.x * 32;
  for (int i = tid; i < 32 * 128; i += 256) {
    int r = i >> 7, c = i & 127;
    int e = e0 + r;
    int t = tgt[e], s = src[e];
    float z = P[t * Cc + c] + Q[s * Cc + c] + b1p[c];
    Z[r][c] = fmaxf(z, 0.f);
  }
  __syncthreads();
  int tx = tid & 31, ty = tid >> 5;
  float acc[4][4] = {};
  #pragma unroll 4
  for (int c = 0; c < 128; ++c) {
    float4 w = *(const float4*)&W2t[c * Cc + tx * 4];
    float z0 = Z[ty * 4 + 0][c], z1 = Z[ty * 4 + 1][c];
    float z2 = Z[ty * 4 + 2][c], z3 = Z[ty * 4 + 3][c];
    acc[0][0] += z0 * w.x; acc[0][1] += z0 * w.y; acc[0][2] += z0 * w.z; acc[0][3] += z0 * w.w;
    acc[1][0] += z1 * w.x; acc[1][1] += z1 * w.y; acc[1][2] += z1 * w.z; acc[1][3] += z1 * w.w;
    acc[2][0] += z2 * w.x; acc[2][1] += z2 * w.y; acc[2][2] += z2 * w.z; acc[2][3] += z2 * w.w;
    acc[3][0] += z3 * w.x; acc[3][1] += z3 * w.y; acc[3][2] += z3 * w.z; acc[3][3] += z3 * w.w;
  }
  float4 bb = *(const float4*)&b2p[tx * 4];
  #pragma unroll
  for (int i = 0; i < 4; ++i) {
    int e = e0 + ty * 4 + i;
    float4 v;
    v.x = fmaxf(acc[i][0] + bb.x, 0.f);
    v.y = fmaxf(acc[i][1] + bb.y, 0.f);
    v.z = fmaxf(acc[i][2] + bb.z, 0.f);
    v.w = fmaxf(acc[i][3] + bb.w, 0.f);
    *(float4*)&out[e * Cc + tx * 4] = v;
  }
}

extern "C" void kernel_launch(void* const* d_in, const int* in_sizes, int n_in,
                              void* d_out, int out_size, void* d_ws, size_t ws_size,
                              hipStream_t stream) {
  (void)in_sizes; (void)n_in; (void)out_size; (void)ws_size;
  const float* x   = (const float*)d_in[0];
  const float* g1  = (const float*)d_in[1];
  const float* be1 = (const float*)d_in[2];
  const float* W1  = (const float*)d_in[3];
  const float* b1  = (const float*)d_in[4];
  const float* g2  = (const float*)d_in[5];
  const float* be2 = (const float*)d_in[6];
  const float* W2  = (const float*)d_in[7];
  const float* b2  = (const float*)d_in[8];
  const int* tgt   = (const int*)d_in[9];
  const int* src   = (const int*)d_in[10];

  float* ws  = (float*)d_ws;
  float* out = (float*)d_out;

  float* P     = ws + WS_P;
  float* Q     = ws + WS_Q;
  float* cntT  = ws + WS_CNTT;
  int*   cntS  = (int*)(ws + WS_CNTS);
  float* stats = ws + WS_STATS;
  float* W1pT  = ws + WS_W1PT;
  float* b1p   = ws + WS_B1P;
  float* W2t   = ws + WS_W2T;
  float* b2p   = ws + WS_B2P;
  float* nbr   = out;  // scratch: overwritten by k_out at the end

  k_zero  <<<dim3((NN + 255) / 256), dim3(256), 0, stream>>>(stats, cntS);
  k_cnt   <<<dim3(NE / 256),        dim3(256), 0, stream>>>(src, cntS);
  k_nbr   <<<dim3(NN),              dim3(Cc),  0, stream>>>(x, tgt, src, nbr, cntT);
  k_stats1<<<dim3(256),             dim3(Cc),  0, stream>>>(nbr, x, cntT, cntS, stats);
  k_fold1 <<<dim3(Cc),              dim3(C2),  0, stream>>>(W1, b1, g1, be1, stats, W1pT, b1p);
  k_pq    <<<dim3(NN / 32, 2),      dim3(256), 0, stream>>>(nbr, x, W1pT, P, Q);
  k_stats2<<<dim3(NE / 512),        dim3(Cc),  0, stream>>>(P, Q, b1p, tgt, src, stats);
  k_fold2 <<<dim3(Cc),              dim3(Cc),  0, stream>>>(W2, b2, g2, be2, stats, W2t, b2p);
  k_out   <<<dim3(NE / 32),         dim3(256), 0, stream>>>(P, Q, b1p, W2t, b2p, tgt, src, out);
}

// Round 8
// 450.967 us; speedup vs baseline: 1.4514x; 1.4514x over previous
//
#include <hip/hip_runtime.h>

#define NN 20000
#define NE 640000
#define Cc 128
#define C2 256
#define BN_EPS 1e-5f

typedef __attribute__((ext_vector_type(8))) short bf16x8;
typedef __attribute__((ext_vector_type(4))) float f32x4;

// ---- workspace layout (float offsets) ----
#define WS_P     0                      // [NN*Cc]
#define WS_Q     (NN*Cc)                // [NN*Cc]
#define WS_CNTT  (2*NN*Cc)              // [NN] float
#define WS_CNTS  (2*NN*Cc + NN)         // [NN] int
#define WS_STATS (2*NN*Cc + 2*NN)       // [768]: sum1[256], sq1[256], sum2[128], sq2[128]
#define WS_W1PT  (WS_STATS + 768)       // [256*128] transposed folded W1: [c][o]
#define WS_B1P   (WS_W1PT + C2*Cc)      // [128]
#define WS_W2BF  (WS_B1P + Cc)         // ushort[128*128] folded W2 in bf16: [o][c] (occupies 8192 floats)
#define WS_B2P   (WS_W2BF + Cc*Cc)      // [128]  (slot kept 16384 floats wide; bf16 uses first half)

// fp32 -> bf16 round-to-nearest-even
static __device__ inline unsigned short f2bf(float f) {
  union { float f; unsigned u; } v; v.f = f;
  unsigned r = v.u + 0x7fffu + ((v.u >> 16) & 1u);
  return (unsigned short)(r >> 16);
}

__global__ void k_zero(float* __restrict__ stats, int* __restrict__ cntS) {
  int i = blockIdx.x * blockDim.x + threadIdx.x;
  if (i < 768) stats[i] = 0.0f;
  if (i < NN) cntS[i] = 0;
}

__global__ void k_cnt(const int* __restrict__ src, int* __restrict__ cntS) {
  int e = blockIdx.x * blockDim.x + threadIdx.x;
  if (e < NE) atomicAdd(&cntS[src[e]], 1);
}

// one block (128 threads) per node: segment sum of x[src] over the node's
// contiguous (tgt sorted) edge range, found by binary search.
__global__ void k_nbr(const float* __restrict__ x, const int* __restrict__ tgt,
                      const int* __restrict__ src, float* __restrict__ nbr,
                      float* __restrict__ cntT) {
  int node = blockIdx.x;
  int a = 0, b = NE;
  while (a < b) { int m = (a + b) >> 1; if (tgt[m] < node) a = m + 1; else b = m; }
  int lo = a;
  b = NE;
  while (a < b) { int m = (a + b) >> 1; if (tgt[m] <= node) a = m + 1; else b = m; }
  int hi = a;
  int c = threadIdx.x;
  float acc = 0.0f;
  for (int e = lo; e < hi; ++e) acc += x[src[e] * Cc + c];
  nbr[node * Cc + c] = acc;
  if (c == 0) cntT[node] = (float)(hi - lo);
}

// BN1 stats: count-weighted sums over nodes.
__global__ void k_stats1(const float* __restrict__ nbr, const float* __restrict__ x,
                         const float* __restrict__ cntT, const int* __restrict__ cntS,
                         float* __restrict__ stats) {
  int c = threadIdx.x;
  float sa = 0.f, qa = 0.f, sb = 0.f, qb = 0.f;
  for (int t = blockIdx.x; t < NN; t += gridDim.x) {
    float ct = cntT[t];
    float cs = (float)cntS[t];
    float v1 = nbr[t * Cc + c];
    float v2 = x[t * Cc + c];
    sa += ct * v1; qa += ct * v1 * v1;
    sb += cs * v2; qb += cs * v2 * v2;
  }
  atomicAdd(&stats[c], sa);
  atomicAdd(&stats[256 + c], qa);
  atomicAdd(&stats[128 + c], sb);
  atomicAdd(&stats[256 + 128 + c], qb);
}

// fold BN1 into W1: W1pT[c][o] = W1[o][c]*a1[c];  b1p[o] = b1[o] + sum_c W1[o][c]*c1[c]
__global__ void k_fold1(const float* __restrict__ W1, const float* __restrict__ b1,
                        const float* __restrict__ g1, const float* __restrict__ be1,
                        const float* __restrict__ stats,
                        float* __restrict__ W1pT, float* __restrict__ b1p) {
  __shared__ float red[C2];
  int o = blockIdx.x, c = threadIdx.x;
  const float inv = 1.0f / (float)NE;
  float mu = stats[c] * inv;
  float var = stats[256 + c] * inv - mu * mu;
  float a = g1[c] * rsqrtf(var + BN_EPS);
  float cc = be1[c] - mu * a;
  float w = W1[o * C2 + c];
  W1pT[c * Cc + o] = w * a;
  red[c] = w * cc;
  __syncthreads();
  for (int s = 128; s > 0; s >>= 1) { if (c < s) red[c] += red[c + s]; __syncthreads(); }
  if (c == 0) b1p[o] = b1[o] + red[0];
}

// P = nbr_sum @ W1a'.T ; Q = x @ W1b'.T   (blockIdx.y selects half)
__global__ __launch_bounds__(256) void k_pq(const float* __restrict__ nbr,
                                            const float* __restrict__ x,
                                            const float* __restrict__ W1pT,
                                            float* __restrict__ P,
                                            float* __restrict__ Q) {
  __shared__ float Ar[32][128];
  const int half = blockIdx.y;
  const float* __restrict__ A = half ? x : nbr;
  float* __restrict__ Out = half ? Q : P;
  const float* __restrict__ Wt = W1pT + (half ? Cc * Cc : 0);  // [128 c][128 o]
  int tid = threadIdx.x;
  int r0 = blockIdx.x * 32;
  for (int i = tid; i < 32 * 128; i += 256) {
    int r = i >> 7, c = i & 127;
    Ar[r][c] = A[(r0 + r) * Cc + c];
  }
  __syncthreads();
  int tx = tid & 31, ty = tid >> 5;
  float acc[4][4] = {};
  #pragma unroll 4
  for (int c = 0; c < 128; ++c) {
    float4 w = *(const float4*)&Wt[c * Cc + tx * 4];
    float a0 = Ar[ty * 4 + 0][c], a1 = Ar[ty * 4 + 1][c];
    float a2 = Ar[ty * 4 + 2][c], a3 = Ar[ty * 4 + 3][c];
    acc[0][0] += a0 * w.x; acc[0][1] += a0 * w.y; acc[0][2] += a0 * w.z; acc[0][3] += a0 * w.w;
    acc[1][0] += a1 * w.x; acc[1][1] += a1 * w.y; acc[1][2] += a1 * w.z; acc[1][3] += a1 * w.w;
    acc[2][0] += a2 * w.x; acc[2][1] += a2 * w.y; acc[2][2] += a2 * w.z; acc[2][3] += a2 * w.w;
    acc[3][0] += a3 * w.x; acc[3][1] += a3 * w.y; acc[3][2] += a3 * w.z; acc[3][3] += a3 * w.w;
  }
  #pragma unroll
  for (int i = 0; i < 4; ++i) {
    int node = r0 + ty * 4 + i;
    float4 v = make_float4(acc[i][0], acc[i][1], acc[i][2], acc[i][3]);
    *(float4*)&Out[node * Cc + tx * 4] = v;
  }
}

// BN2 stats: one pass over edges, z recomputed from P,Q (L2-resident).
__global__ void k_stats2(const float* __restrict__ P, const float* __restrict__ Q,
                         const float* __restrict__ b1p,
                         const int* __restrict__ tgt, const int* __restrict__ src,
                         float* __restrict__ stats) {
  int c = threadIdx.x;
  int e0 = blockIdx.x * 512;
  float b = b1p[c];
  float s = 0.f, q = 0.f;
  for (int e = e0; e < e0 + 512; ++e) {
    int t = tgt[e], sc = src[e];
    float z = P[t * Cc + c] + Q[sc * Cc + c] + b;
    z = fmaxf(z, 0.f);
    s += z; q += z * z;
  }
  atomicAdd(&stats[512 + c], s);
  atomicAdd(&stats[640 + c], q);
}

// fold BN2 into W2, emit bf16 [o][c] weights + fp32 bias
__global__ void k_fold2(const float* __restrict__ W2, const float* __restrict__ b2,
                        const float* __restrict__ g2, const float* __restrict__ be2,
                        const float* __restrict__ stats,
                        unsigned short* __restrict__ W2bf, float* __restrict__ b2p) {
  __shared__ float red[Cc];
  int o = blockIdx.x, c = threadIdx.x;
  const float inv = 1.0f / (float)NE;
  float mu = stats[512 + c] * inv;
  float var = stats[640 + c] * inv - mu * mu;
  float a = g2[c] * rsqrtf(var + BN_EPS);
  float cc = be2[c] - mu * a;
  float w = W2[o * Cc + c];
  W2bf[o * Cc + c] = f2bf(w * a);
  red[c] = w * cc;
  __syncthreads();
  for (int s = 64; s > 0; s >>= 1) { if (c < s) red[c] += red[c + s]; __syncthreads(); }
  if (c == 0) b2p[o] = b2[o] + red[0];
}

// out[e][o] = relu( sum_c z[e][c]*W2'[o][c] + b2'[o] ), bf16 MFMA.
// 64 edges x 128 outs per block, 4 waves; wave w owns edges [w*16, w*16+16).
// LDS rows padded to 136 bf16 (272 B): consecutive rows 4 banks apart -> ~2-way (free).
#define ZPAD 136
__global__ __launch_bounds__(256) void k_out_mfma(const float* __restrict__ P,
                                                  const float* __restrict__ Q,
                                                  const float* __restrict__ b1p,
                                                  const unsigned short* __restrict__ W2bf,
                                                  const float* __restrict__ b2p,
                                                  const int* __restrict__ tgt,
                                                  const int* __restrict__ src,
                                                  float* __restrict__ out) {
  __shared__ unsigned short Zl[64 * ZPAD];   // 17408 B
  __shared__ unsigned short Wl[128 * ZPAD];  // 34816 B
  int tid = threadIdx.x;
  int e0 = blockIdx.x * 64;

  // stage folded-bf16 W2 [o][c] -> LDS (coalesced 16B loads)
  for (int i = tid; i < 2048; i += 256) {
    int row = i >> 4, col = (i & 15) * 8;
    *(bf16x8*)&Wl[row * ZPAD + col] = *(const bf16x8*)&W2bf[row * Cc + col];
  }
  // stage Z = relu(P[tgt]+Q[src]+b1') in bf16; 4 threads per edge-row
  {
    int r = tid >> 2;
    int c0 = (tid & 3) * 32;
    int e = e0 + r;
    const float* Pr = P + (size_t)tgt[e] * Cc;
    const float* Qr = Q + (size_t)src[e] * Cc;
    #pragma unroll
    for (int j = 0; j < 4; ++j) {
      int c = c0 + j * 8;
      float4 p0 = *(const float4*)&Pr[c];
      float4 p1 = *(const float4*)&Pr[c + 4];
      float4 q0 = *(const float4*)&Qr[c];
      float4 q1 = *(const float4*)&Qr[c + 4];
      float4 b0 = *(const float4*)&b1p[c];
      float4 b1 = *(const float4*)&b1p[c + 4];
      bf16x8 z;
      z[0] = (short)f2bf(fmaxf(p0.x + q0.x + b0.x, 0.f));
      z[1] = (short)f2bf(fmaxf(p0.y + q0.y + b0.y, 0.f));
      z[2] = (short)f2bf(fmaxf(p0.z + q0.z + b0.z, 0.f));
      z[3] = (short)f2bf(fmaxf(p0.w + q0.w + b0.w, 0.f));
      z[4] = (short)f2bf(fmaxf(p1.x + q1.x + b1.x, 0.f));
      z[5] = (short)f2bf(fmaxf(p1.y + q1.y + b1.y, 0.f));
      z[6] = (short)f2bf(fmaxf(p1.z + q1.z + b1.z, 0.f));
      z[7] = (short)f2bf(fmaxf(p1.w + q1.w + b1.w, 0.f));
      *(bf16x8*)&Zl[r * ZPAD + c] = z;
    }
  }
  __syncthreads();

  int w = tid >> 6, l = tid & 63;
  int la = l & 15, kb = l >> 4;           // A row / B col = la; k-block = kb*8
  f32x4 acc[8];
  #pragma unroll
  for (int n = 0; n < 8; ++n) acc[n] = (f32x4){0.f, 0.f, 0.f, 0.f};

  #pragma unroll
  for (int kk = 0; kk < 4; ++kk) {        // K = 128 in 4 steps of 32
    bf16x8 a = *(const bf16x8*)&Zl[(w * 16 + la) * ZPAD + kk * 32 + kb * 8];
    #pragma unroll
    for (int n = 0; n < 8; ++n) {         // 8 out-tiles of 16
      bf16x8 b = *(const bf16x8*)&Wl[(n * 16 + la) * ZPAD + kk * 32 + kb * 8];
      acc[n] = __builtin_amdgcn_mfma_f32_16x16x32_bf16(a, b, acc[n], 0, 0, 0);
    }
  }

  // C/D layout (m89-verified): col = l&15, row = (l>>4)*4 + reg
  int r0 = kb * 4;
  #pragma unroll
  for (int n = 0; n < 8; ++n) {
    int col = n * 16 + la;
    float bb = b2p[col];
    #pragma unroll
    for (int r = 0; r < 4; ++r) {
      int e = e0 + w * 16 + r0 + r;
      out[(size_t)e * Cc + col] = fmaxf(acc[n][r] + bb, 0.f);
    }
  }
}

extern "C" void kernel_launch(void* const* d_in, const int* in_sizes, int n_in,
                              void* d_out, int out_size, void* d_ws, size_t ws_size,
                              hipStream_t stream) {
  (void)in_sizes; (void)n_in; (void)out_size; (void)ws_size;
  const float* x   = (const float*)d_in[0];
  const float* g1  = (const float*)d_in[1];
  const float* be1 = (const float*)d_in[2];
  const float* W1  = (const float*)d_in[3];
  const float* b1  = (const float*)d_in[4];
  const float* g2  = (const float*)d_in[5];
  const float* be2 = (const float*)d_in[6];
  const float* W2  = (const float*)d_in[7];
  const float* b2  = (const float*)d_in[8];
  const int* tgt   = (const int*)d_in[9];
  const int* src   = (const int*)d_in[10];

  float* ws  = (float*)d_ws;
  float* out = (float*)d_out;

  float* P     = ws + WS_P;
  float* Q     = ws + WS_Q;
  float* cntT  = ws + WS_CNTT;
  int*   cntS  = (int*)(ws + WS_CNTS);
  float* stats = ws + WS_STATS;
  float* W1pT  = ws + WS_W1PT;
  float* b1p   = ws + WS_B1P;
  unsigned short* W2bf = (unsigned short*)(ws + WS_W2BF);
  float* b2p   = ws + WS_B2P;
  float* nbr   = out;  // scratch: overwritten by k_out_mfma at the end

  k_zero  <<<dim3((NN + 255) / 256), dim3(256), 0, stream>>>(stats, cntS);
  k_cnt   <<<dim3(NE / 256),        dim3(256), 0, stream>>>(src, cntS);
  k_nbr   <<<dim3(NN),              dim3(Cc),  0, stream>>>(x, tgt, src, nbr, cntT);
  k_stats1<<<dim3(256),             dim3(Cc),  0, stream>>>(nbr, x, cntT, cntS, stats);
  k_fold1 <<<dim3(Cc),              dim3(C2),  0, stream>>>(W1, b1, g1, be1, stats, W1pT, b1p);
  k_pq    <<<dim3(NN / 32, 2),      dim3(256), 0, stream>>>(nbr, x, W1pT, P, Q);
  k_stats2<<<dim3(NE / 512),        dim3(Cc),  0, stream>>>(P, Q, b1p, tgt, src, stats);
  k_fold2 <<<dim3(Cc),              dim3(Cc),  0, stream>>>(W2, b2, g2, be2, stats, W2bf, b2p);
  k_out_mfma<<<dim3(NE / 64),       dim3(256), 0, stream>>>(P, Q, b1p, W2bf, b2p, tgt, src, out);
}